// Round 1
// baseline (102.879 us; speedup 1.0000x reference)
//
#include <hip/hip_runtime.h>

// QuantumDMRGLayer: B=2048, L=196, M=16, NBL=10, pos_label=98 (fixed by setup).
// Layout plan:
//   - 512 blocks x 128 threads. Block owns 4 samples. Wave 0 = left sweeps
//     (sites 0..97 of A_mid, ascending), wave 1 = right sweeps (sites 193..98,
//     descending). Lane n of each 16-lane group owns component v[n] of one
//     sample's running bond vector.
//   - Per site: v'[n] = x0 * sum_m v[m] A0[m][n] + x1 * sum_m v[m] A1[m][n].
//     The m-sum runs in XOR order r=0..15 using ds_swizzle (xor=r) to fetch
//     v[n^r]; A is staged in LDS pre-permuted so step r reads slot [n][r] =
//     A[n^r][n] (left) / [m][r] = A[m][m^r] (right). Rows padded to 20 floats.
//   - A tiles double-buffered in LDS, 4 sites/chunk, global loads hoisted
//     before compute, scatter ds_writes after (latency hidden), 1 barrier/chunk.
//   - x rows and T_out staged once; final T contraction done by 40 threads.

#define XR 392          // floats per sample row of inputs (196*2)
#define MROW 20         // padded LDS row stride (floats)
#define MATF 320        // floats per 16x16 matrix in LDS (16*20)
#define CHF 2560        // floats per chunk per stream (4 sites * 2 mats * 320)

#define SWZ_STEP(r, e0, e1)                                                    \
    { float vv = __int_as_float(__builtin_amdgcn_ds_swizzle(                   \
          __float_as_int(v), 0x1F | ((r) << 10)));                             \
      acc0 = fmaf(vv, (e0), acc0); acc1 = fmaf(vv, (e1), acc1); }

__global__ __launch_bounds__(128)
void QuantumDMRGLayer_kernel(const float* __restrict__ X,
                             const float* __restrict__ AL,
                             const float* __restrict__ AM,
                             const float* __restrict__ AR,
                             const float* __restrict__ T,
                             float* __restrict__ OUT)
{
    __shared__ float sA[2][2][CHF];   // [buf][stream(0=left,1=right)][...]
    __shared__ float sX[4 * XR];      // 4 sample rows of inputs
    __shared__ float sT[2560];        // T_out (16,16,10)
    __shared__ float sV[4][2][16];    // final left/right vectors per sample

    const int tid  = threadIdx.x;
    const int wv   = tid >> 6;        // 0 = left sweep wave, 1 = right
    const int lane = tid & 63;
    const int g    = lane >> 4;       // sample slot 0..3 within block
    const int n    = lane & 15;       // vector component owned by this lane
    const int b0   = (int)blockIdx.x << 2;

    // ---- prologue staging: x rows (4 x 392 floats) and T_out ----
    for (int k = tid; k < 4 * 98; k += 128) {
        const int smp = k / 98, w = k - smp * 98;
        const float4 v4 = ((const float4*)(X + (size_t)(b0 + smp) * XR))[w];
        ((float4*)(sX + smp * XR))[w] = v4;
    }
    for (int k = tid; k < 640; k += 128)
        ((float4*)sT)[k] = ((const float4*)T)[k];

    float4 st[8];   // staging registers: 4 float4 left stream + 4 right

    // Load 4 sites (chunk cc) of both streams: 1024 float4 over 128 threads.
    auto stage_load = [&](int cc) {
#pragma unroll
        for (int k = 0; k < 4; ++k) {
            const int flat = k * 128 + tid;      // 0..511
            const int sl   = flat >> 7;          // site-in-chunk 0..3
            const int rem  = flat & 127;         // (d,m,q) within site
            const int idxL = cc * 4 + sl;        // left site 0..99 (always in range)
            const int idxR = 193 - (cc * 4 + sl);// right site (descending)
            st[k]     = ((const float4*)AM)[idxL * 128 + rem];
            st[4 + k] = ((const float4*)AM)[idxR * 128 + rem];
        }
    };
    // Scatter into LDS with the XOR permutation baked into the address.
    auto stage_write = [&](int buf) {
#pragma unroll
        for (int k = 0; k < 4; ++k) {
            const int flat = k * 128 + tid;
            const int sl = flat >> 7, rem = flat & 127;
            const int d = rem >> 6, m = (rem >> 2) & 15, q = rem & 3;
            const int base = (sl * 2 + d) * MATF;
            const float lv[4] = { st[k].x, st[k].y, st[k].z, st[k].w };
            const float rv[4] = { st[4+k].x, st[4+k].y, st[4+k].z, st[4+k].w };
#pragma unroll
            for (int i = 0; i < 4; ++i) {
                const int nn = q * 4 + i;
                const int r  = m ^ nn;
                sA[buf][0][base + nn * MROW + r] = lv[i];  // left: row nn
                sA[buf][1][base + m  * MROW + r] = rv[i];  // right: row m
            }
        }
    };

    stage_load(0);
    stage_write(0);
    __syncthreads();

    // ---- init bond vector ----
    const float* Ab = (wv == 0) ? AL : AR;
    const float2 x0 = *(const float2*)(sX + g * XR + (wv == 0 ? 0 : 390));
    float v = x0.x * Ab[n] + x0.y * Ab[16 + n];

    // ---- main chain loop: 25 chunks of up to 4 sites ----
    const int lim = (wv == 0) ? 98 : 96;
    for (int c = 0; c < 25; ++c) {
        if (c < 24) stage_load(c + 1);
        const float* As = sA[c & 1][wv];
#pragma unroll
        for (int j = 0; j < 4; ++j) {
            const int idx = c * 4 + j;
            if (idx >= lim) break;
            // x pair for this site: left site s=idx -> inputs[:,1+idx];
            // right s=193-idx -> inputs[:,194-idx]
            const int xo = (wv == 0) ? (2 + 2 * idx) : (2 * (194 - idx));
            const float2 xs = *(const float2*)(sX + g * XR + xo);
            const float* r0 = As + (j * 2) * MATF + n * MROW;
            const float* r1 = r0 + MATF;
            const float4 A0 = *(const float4*)(r0);
            const float4 A1 = *(const float4*)(r0 + 4);
            const float4 A2 = *(const float4*)(r0 + 8);
            const float4 A3 = *(const float4*)(r0 + 12);
            const float4 B0 = *(const float4*)(r1);
            const float4 B1 = *(const float4*)(r1 + 4);
            const float4 B2 = *(const float4*)(r1 + 8);
            const float4 B3 = *(const float4*)(r1 + 12);
            float acc0 = v * A0.x;
            float acc1 = v * B0.x;
            SWZ_STEP(1,  A0.y, B0.y)
            SWZ_STEP(2,  A0.z, B0.z)
            SWZ_STEP(3,  A0.w, B0.w)
            SWZ_STEP(4,  A1.x, B1.x)
            SWZ_STEP(5,  A1.y, B1.y)
            SWZ_STEP(6,  A1.z, B1.z)
            SWZ_STEP(7,  A1.w, B1.w)
            SWZ_STEP(8,  A2.x, B2.x)
            SWZ_STEP(9,  A2.y, B2.y)
            SWZ_STEP(10, A2.z, B2.z)
            SWZ_STEP(11, A2.w, B2.w)
            SWZ_STEP(12, A3.x, B3.x)
            SWZ_STEP(13, A3.y, B3.y)
            SWZ_STEP(14, A3.z, B3.z)
            SWZ_STEP(15, A3.w, B3.w)
            v = fmaf(xs.x, acc0, xs.y * acc1);
        }
        if (c < 24) stage_write((c + 1) & 1);
        __syncthreads();
    }

    // ---- epilogue: out[b][l] = sum_{m,n} left[m] T[m][n][l] right[n] ----
    sV[g][wv][n] = v;
    __syncthreads();
    if (tid < 40) {
        const int sm = tid / 10;
        const int l  = tid - sm * 10;
        const float* Rv = &sV[sm][1][0];
        const float4 Ra = *(const float4*)(Rv);
        const float4 Rb = *(const float4*)(Rv + 4);
        const float4 Rc = *(const float4*)(Rv + 8);
        const float4 Rd = *(const float4*)(Rv + 12);
        float acc = 0.f;
#pragma unroll
        for (int m = 0; m < 16; ++m) {
            const float lm = sV[sm][0][m];
            const float* Tp = sT + m * 160 + l;
            acc = fmaf(lm * Ra.x, Tp[0],   acc);
            acc = fmaf(lm * Ra.y, Tp[10],  acc);
            acc = fmaf(lm * Ra.z, Tp[20],  acc);
            acc = fmaf(lm * Ra.w, Tp[30],  acc);
            acc = fmaf(lm * Rb.x, Tp[40],  acc);
            acc = fmaf(lm * Rb.y, Tp[50],  acc);
            acc = fmaf(lm * Rb.z, Tp[60],  acc);
            acc = fmaf(lm * Rb.w, Tp[70],  acc);
            acc = fmaf(lm * Rc.x, Tp[80],  acc);
            acc = fmaf(lm * Rc.y, Tp[90],  acc);
            acc = fmaf(lm * Rc.z, Tp[100], acc);
            acc = fmaf(lm * Rc.w, Tp[110], acc);
            acc = fmaf(lm * Rd.x, Tp[120], acc);
            acc = fmaf(lm * Rd.y, Tp[130], acc);
            acc = fmaf(lm * Rd.z, Tp[140], acc);
            acc = fmaf(lm * Rd.w, Tp[150], acc);
        }
        OUT[(b0 + sm) * 10 + l] = acc;
    }
}

extern "C" void kernel_launch(void* const* d_in, const int* in_sizes, int n_in,
                              void* d_out, int out_size, void* d_ws, size_t ws_size,
                              hipStream_t stream)
{
    const float* X  = (const float*)d_in[0];   // (2048,196,2)
    const float* AL = (const float*)d_in[1];   // (2,16)
    const float* AM = (const float*)d_in[2];   // (194,2,16,16)
    const float* AR = (const float*)d_in[3];   // (2,16)
    const float* T  = (const float*)d_in[4];   // (16,16,10)
    (void)in_sizes; (void)n_in; (void)out_size; (void)d_ws; (void)ws_size;
    float* OUT = (float*)d_out;                // (2048,10)
    hipLaunchKernelGGL(QuantumDMRGLayer_kernel, dim3(512), dim3(128), 0, stream,
                       X, AL, AM, AR, T, OUT);
}

// Round 2
// 96.776 us; speedup vs baseline: 1.0631x; 1.0631x over previous
//
#include <hip/hip_runtime.h>

// QuantumDMRGLayer: B=2048, L=196, M=16, NBL=10, pos_label=98 (fixed by setup).
//   - 512 blocks x 128 threads. Block owns 4 samples. Wave 0 = left sweeps
//     (sites 0..97), wave 1 = right sweeps (sites 193..98). Lane n of each
//     16-lane group owns component v[n] of one sample's bond vector.
//   - Per site: v'[n] = x0*sum_m v[m]A0[m][n] + x1*sum_m v[m]A1[m][n].
//     The m-sum runs in ROTATION order r=0..15 using DPP row_ror:r
//     (dst[i] = src[(i-r)&15]) -- VALU pipe, not DS pipe (round 1 showed the
//     15 ds_swizzle/site made the kernel DS-latency bound at 1300 cyc/site).
//     A is staged in LDS pre-permuted so step r reads slot [n][r]:
//       left:  A[i][j] -> row j, slot (j-i)&15
//       right: A[i][j] -> row i, slot (i-j)&15
//     Rows padded to 20 floats (16B-aligned, 2-way bank alias only).
//   - A tiles double-buffered in LDS, 4 sites/chunk, global loads hoisted
//     before compute, scatter ds_writes after, 1 barrier/chunk. Ragged tail
//     (left sites 96,97) peeled out of the hot loop.

#define XR 392          // floats per sample row of inputs (196*2)
#define MROW 20         // padded LDS row stride (floats)
#define MATF 320        // floats per 16x16 matrix in LDS (16*20)
#define CHF 2560        // floats per chunk per stream (4 sites * 2 mats * 320)

#define ROR_STEP(r, e0, e1)                                                    \
    { float vv = __int_as_float(__builtin_amdgcn_update_dpp(                   \
          __float_as_int(v), __float_as_int(v), 0x120 + (r), 0xF, 0xF, false));\
      acc0 = fmaf(vv, (e0), acc0); acc1 = fmaf(vv, (e1), acc1); }

__global__ __launch_bounds__(128)
void QuantumDMRGLayer_kernel(const float* __restrict__ X,
                             const float* __restrict__ AL,
                             const float* __restrict__ AM,
                             const float* __restrict__ AR,
                             const float* __restrict__ T,
                             float* __restrict__ OUT)
{
    __shared__ float sA[2][2][CHF];   // [buf][stream(0=left,1=right)][...]
    __shared__ float sX[4 * XR];      // 4 sample rows of inputs
    __shared__ float sT[2560];        // T_out (16,16,10)
    __shared__ float sV[4][2][16];    // final left/right vectors per sample

    const int tid  = threadIdx.x;
    const int wv   = tid >> 6;        // 0 = left sweep wave, 1 = right
    const int lane = tid & 63;
    const int g    = lane >> 4;       // sample slot 0..3 within block
    const int n    = lane & 15;       // vector component owned by this lane
    const int b0   = (int)blockIdx.x << 2;

    // ---- prologue staging: x rows (4 x 392 floats) and T_out ----
    for (int k = tid; k < 4 * 98; k += 128) {
        const int smp = k / 98, w = k - smp * 98;
        const float4 v4 = ((const float4*)(X + (size_t)(b0 + smp) * XR))[w];
        ((float4*)(sX + smp * XR))[w] = v4;
    }
    for (int k = tid; k < 640; k += 128)
        ((float4*)sT)[k] = ((const float4*)T)[k];

    float4 st[8];   // staging registers: 4 float4 left stream + 4 right

    // Load 4 sites (chunk cc) of both streams: 1024 float4 over 128 threads.
    auto stage_load = [&](int cc) {
#pragma unroll
        for (int k = 0; k < 4; ++k) {
            const int flat = k * 128 + tid;      // 0..511
            const int sl   = flat >> 7;          // site-in-chunk 0..3
            const int rem  = flat & 127;         // (d,i,q) within site
            const int idxL = cc * 4 + sl;        // left site (<=99, in range)
            const int idxR = 193 - (cc * 4 + sl);// right site (descending)
            st[k]     = ((const float4*)AM)[idxL * 128 + rem];
            st[4 + k] = ((const float4*)AM)[idxR * 128 + rem];
        }
    };
    // Scatter into LDS with the rotation permutation baked into the address.
    auto stage_write = [&](int buf) {
#pragma unroll
        for (int k = 0; k < 4; ++k) {
            const int flat = k * 128 + tid;
            const int sl = flat >> 7, rem = flat & 127;
            const int d = rem >> 6, m = (rem >> 2) & 15, q = rem & 3;
            const int base = (sl * 2 + d) * MATF;
            const float lv[4] = { st[k].x, st[k].y, st[k].z, st[k].w };
            const float rv[4] = { st[4+k].x, st[4+k].y, st[4+k].z, st[4+k].w };
#pragma unroll
            for (int i = 0; i < 4; ++i) {
                const int nn = q * 4 + i;          // column j
                const int rL = (nn - m) & 15;      // left slot
                const int rR = (m - nn) & 15;      // right slot
                sA[buf][0][base + nn * MROW + rL] = lv[i];  // left: row j
                sA[buf][1][base + m  * MROW + rR] = rv[i];  // right: row i
            }
        }
    };

    // One site update: v <- x0*(v@A0) + x1*(v@A1) (left) / matching right form.
    auto site_step = [&](const float* As, int j, int idx, float& v) {
        const int xo = (wv == 0) ? (2 + 2 * idx) : (388 - 2 * idx);
        const float2 xs = *(const float2*)(sX + g * XR + xo);
        const float* r0 = As + (j * 2) * MATF + n * MROW;
        const float* r1 = r0 + MATF;
        const float4 A0 = *(const float4*)(r0);
        const float4 A1 = *(const float4*)(r0 + 4);
        const float4 A2 = *(const float4*)(r0 + 8);
        const float4 A3 = *(const float4*)(r0 + 12);
        const float4 B0 = *(const float4*)(r1);
        const float4 B1 = *(const float4*)(r1 + 4);
        const float4 B2 = *(const float4*)(r1 + 8);
        const float4 B3 = *(const float4*)(r1 + 12);
        float acc0 = v * A0.x;       // r=0: vv = v (diagonal slot)
        float acc1 = v * B0.x;
        ROR_STEP(1,  A0.y, B0.y)
        ROR_STEP(2,  A0.z, B0.z)
        ROR_STEP(3,  A0.w, B0.w)
        ROR_STEP(4,  A1.x, B1.x)
        ROR_STEP(5,  A1.y, B1.y)
        ROR_STEP(6,  A1.z, B1.z)
        ROR_STEP(7,  A1.w, B1.w)
        ROR_STEP(8,  A2.x, B2.x)
        ROR_STEP(9,  A2.y, B2.y)
        ROR_STEP(10, A2.z, B2.z)
        ROR_STEP(11, A2.w, B2.w)
        ROR_STEP(12, A3.x, B3.x)
        ROR_STEP(13, A3.y, B3.y)
        ROR_STEP(14, A3.z, B3.z)
        ROR_STEP(15, A3.w, B3.w)
        v = fmaf(xs.x, acc0, xs.y * acc1);
    };

    stage_load(0);
    stage_write(0);
    __syncthreads();

    // ---- init bond vector ----
    const float* Ab = (wv == 0) ? AL : AR;
    const float2 x0 = *(const float2*)(sX + g * XR + (wv == 0 ? 0 : 390));
    float v = x0.x * Ab[n] + x0.y * Ab[16 + n];

    // ---- main chain loop: 24 full chunks of 4 sites (96 sites/stream) ----
    for (int c = 0; c < 24; ++c) {
        stage_load(c + 1);
        const float* As = sA[c & 1][wv];
#pragma unroll
        for (int j = 0; j < 4; ++j)
            site_step(As, j, c * 4 + j, v);
        stage_write((c + 1) & 1);
        __syncthreads();
    }
    // ---- tail: left stream has 2 more sites (96, 97) in buf 0 ----
    if (wv == 0) {
        const float* As = sA[0][0];
        site_step(As, 0, 96, v);
        site_step(As, 1, 97, v);
    }

    // ---- epilogue: out[b][l] = sum_{m,n} left[m] T[m][n][l] right[n] ----
    sV[g][wv][n] = v;
    __syncthreads();
    if (tid < 40) {
        const int sm = tid / 10;
        const int l  = tid - sm * 10;
        const float* Rv = &sV[sm][1][0];
        const float4 Ra = *(const float4*)(Rv);
        const float4 Rb = *(const float4*)(Rv + 4);
        const float4 Rc = *(const float4*)(Rv + 8);
        const float4 Rd = *(const float4*)(Rv + 12);
        float acc = 0.f;
#pragma unroll
        for (int m = 0; m < 16; ++m) {
            const float lm = sV[sm][0][m];
            const float* Tp = sT + m * 160 + l;
            acc = fmaf(lm * Ra.x, Tp[0],   acc);
            acc = fmaf(lm * Ra.y, Tp[10],  acc);
            acc = fmaf(lm * Ra.z, Tp[20],  acc);
            acc = fmaf(lm * Ra.w, Tp[30],  acc);
            acc = fmaf(lm * Rb.x, Tp[40],  acc);
            acc = fmaf(lm * Rb.y, Tp[50],  acc);
            acc = fmaf(lm * Rb.z, Tp[60],  acc);
            acc = fmaf(lm * Rb.w, Tp[70],  acc);
            acc = fmaf(lm * Rc.x, Tp[80],  acc);
            acc = fmaf(lm * Rc.y, Tp[90],  acc);
            acc = fmaf(lm * Rc.z, Tp[100], acc);
            acc = fmaf(lm * Rc.w, Tp[110], acc);
            acc = fmaf(lm * Rd.x, Tp[120], acc);
            acc = fmaf(lm * Rd.y, Tp[130], acc);
            acc = fmaf(lm * Rd.z, Tp[140], acc);
            acc = fmaf(lm * Rd.w, Tp[150], acc);
        }
        OUT[(b0 + sm) * 10 + l] = acc;
    }
}

extern "C" void kernel_launch(void* const* d_in, const int* in_sizes, int n_in,
                              void* d_out, int out_size, void* d_ws, size_t ws_size,
                              hipStream_t stream)
{
    const float* X  = (const float*)d_in[0];   // (2048,196,2)
    const float* AL = (const float*)d_in[1];   // (2,16)
    const float* AM = (const float*)d_in[2];   // (194,2,16,16)
    const float* AR = (const float*)d_in[3];   // (2,16)
    const float* T  = (const float*)d_in[4];   // (16,16,10)
    (void)in_sizes; (void)n_in; (void)out_size; (void)d_ws; (void)ws_size;
    float* OUT = (float*)d_out;                // (2048,10)
    hipLaunchKernelGGL(QuantumDMRGLayer_kernel, dim3(512), dim3(128), 0, stream,
                       X, AL, AM, AR, T, OUT);
}